// Round 1
// baseline (98.581 us; speedup 1.0000x reference)
//
#include <hip/hip_runtime.h>
#include <stdint.h>

#define NROWS 4096
#define DIM   512
#define BK    32
#define TILE  128
#define NBLK  32            // NROWS / TILE
#define NPAIR 528           // NBLK*(NBLK+1)/2

typedef float f32x4 __attribute__((ext_vector_type(4)));
typedef short s16x8 __attribute__((ext_vector_type(8)));

// workspace layout (bytes)
#define OFF_XB   0u
#define OFF_SQ   (NROWS * DIM * 2u)          // 4,194,304
#define OFF_LAB  (OFF_SQ + NROWS * 4u)       // + 16 KB
#define OFF_ACC  (OFF_LAB + NROWS * 4u)      // + 16 KB

__device__ __forceinline__ unsigned short f2bf(float f) {
  unsigned u = __float_as_uint(f);
  return (unsigned short)((u + 0x7FFFu + ((u >> 16) & 1u)) >> 16);
}

typedef __attribute__((address_space(1))) unsigned int glb_uint;
typedef __attribute__((address_space(3))) unsigned int lds_uint;

__device__ __forceinline__ void gl2lds16(const void* g, void* l) {
  __builtin_amdgcn_global_load_lds(
      (glb_uint*)(uintptr_t)g,
      (lds_uint*)(unsigned int)(uintptr_t)l,
      16, 0, 0);
}

// ---------------- prep: fp32 -> bf16, sq rows (fp32 exact), labels -> i32, zero accum
__global__ __launch_bounds__(256) void prep_kernel(
    const float* __restrict__ X, const long long* __restrict__ lab,
    unsigned short* __restrict__ Xb, float* __restrict__ sq,
    int* __restrict__ labi, float* __restrict__ accum)
{
  int t = threadIdx.x;
  int gid = blockIdx.x * 256 + t;
  if (gid < 4) accum[gid] = 0.0f;               // sum1, sum2, cnt(bits), pad
  if (gid < NROWS) labi[gid] = (int)lab[gid];

  int wave = t >> 6, lane = t & 63;
  int row = blockIdx.x * 4 + wave;              // 1024 blocks * 4 rows
  const float4* Xr = (const float4*)(X + (size_t)row * DIM);
  float4 a = Xr[lane * 2];
  float4 b = Xr[lane * 2 + 1];

  uint4 pk;
  pk.x = (unsigned)f2bf(a.x) | ((unsigned)f2bf(a.y) << 16);
  pk.y = (unsigned)f2bf(a.z) | ((unsigned)f2bf(a.w) << 16);
  pk.z = (unsigned)f2bf(b.x) | ((unsigned)f2bf(b.y) << 16);
  pk.w = (unsigned)f2bf(b.z) | ((unsigned)f2bf(b.w) << 16);
  *(uint4*)(Xb + (size_t)row * DIM + lane * 8) = pk;

  float s = a.x*a.x + a.y*a.y + a.z*a.z + a.w*a.w
          + b.x*b.x + b.y*b.y + b.z*b.z + b.w*b.w;
  #pragma unroll
  for (int off = 32; off; off >>= 1) s += __shfl_down(s, off, 64);
  if (lane == 0) sq[row] = s;
}

// ---------------- main: symmetric tiled X*X^T with fused loss epilogue
__global__ __launch_bounds__(256) void pair_kernel(
    const unsigned short* __restrict__ Xb, const float* __restrict__ sq,
    const int* __restrict__ labi, const float* __restrict__ marginp,
    float* __restrict__ accum)
{
  __shared__ unsigned short As[TILE * BK];   // 8 KB, row-major [128][32], no pad
  __shared__ unsigned short Bs[TILE * BK];   // 8 KB
  __shared__ float sRow[TILE], sCol[TILE];
  __shared__ int   lRow[TILE], lCol[TILE];
  __shared__ float rs1[4], rs2[4];
  __shared__ int   rc[4];

  int t = threadIdx.x;

  // linear block -> (bi, bj) with bi <= bj
  int rem = blockIdx.x, bi = 0;
  while (rem >= (NBLK - bi)) { rem -= (NBLK - bi); bi++; }
  int bj = bi + rem;

  int wave = t >> 6, lane = t & 63;
  int quad = lane >> 4, ml = lane & 15;
  int waveRow = (wave >> 1) * 64, waveCol = (wave & 1) * 64;

  f32x4 acc[4][4] = {};

  // staging addresses: thread t loads 8 bf16 (16 B); LDS dest = t*16 bytes (wave-contiguous)
  const int r0 = t >> 2;              // 0..63
  const int c0 = (t & 3) * 8;         // k-element offset within BK
  const size_t gA0 = (size_t)(bi * TILE +       r0) * DIM + c0;
  const size_t gA1 = (size_t)(bi * TILE + 64 +  r0) * DIM + c0;
  const size_t gB0 = (size_t)(bj * TILE +       r0) * DIM + c0;
  const size_t gB1 = (size_t)(bj * TILE + 64 +  r0) * DIM + c0;

  const s16x8* Ap = (const s16x8*)As;
  const s16x8* Bp = (const s16x8*)Bs;

  for (int kt = 0; kt < DIM / BK; ++kt) {
    __syncthreads();                  // prev iteration's LDS reads done
    size_t ko = (size_t)kt * BK;
    gl2lds16(Xb + gA0 + ko, (void*)(As + t * 8));
    gl2lds16(Xb + gA1 + ko, (void*)(As + 2048 + t * 8));
    gl2lds16(Xb + gB0 + ko, (void*)(Bs + t * 8));
    gl2lds16(Xb + gB1 + ko, (void*)(Bs + 2048 + t * 8));
    __syncthreads();                  // vmcnt drained by compiler before barrier

    s16x8 af[4], bfr[4];
    #pragma unroll
    for (int r = 0; r < 4; ++r)
      af[r] = Ap[(waveRow + r * 16 + ml) * 4 + quad];
    #pragma unroll
    for (int c = 0; c < 4; ++c)
      bfr[c] = Bp[(waveCol + c * 16 + ml) * 4 + quad];

    #pragma unroll
    for (int r = 0; r < 4; ++r)
      #pragma unroll
      for (int c = 0; c < 4; ++c)
        acc[r][c] = __builtin_amdgcn_mfma_f32_16x16x32_bf16(af[r], bfr[c], acc[r][c], 0, 0, 0);
  }

  // stage sq/label tiles for the epilogue
  if (t < TILE) {
    sRow[t] = sq[bi * TILE + t];
    lRow[t] = labi[bi * TILE + t];
  } else {
    int u = t - TILE;
    sCol[u] = sq[bj * TILE + u];
    lCol[u] = labi[bj * TILE + u];
  }
  __syncthreads();

  float margin = *marginp;
  float s1 = 0.f, s2 = 0.f;
  int cnt = 0;
  #pragma unroll
  for (int c = 0; c < 4; ++c) {
    int col = waveCol + c * 16 + ml;
    float sqc = sCol[col];
    int lc = lCol[col];
    #pragma unroll
    for (int r = 0; r < 4; ++r) {
      int rbase = waveRow + r * 16 + quad * 4;   // C/D layout: row=(lane>>4)*4+reg, col=lane&15
      #pragma unroll
      for (int i = 0; i < 4; ++i) {
        int row = rbase + i;
        float d = sRow[row] + sqc - 2.0f * acc[r][c][i];
        d = fmaxf(d, 0.0f);
        if (lRow[row] == lc) { s1 += d; cnt++; }
        else                 { s2 += fmaxf(margin - d, 0.0f); }
      }
    }
  }

  #pragma unroll
  for (int off = 32; off; off >>= 1) {
    s1  += __shfl_down(s1, off, 64);
    s2  += __shfl_down(s2, off, 64);
    cnt += __shfl_down(cnt, off, 64);
  }
  if (lane == 0) { rs1[wave] = s1; rs2[wave] = s2; rc[wave] = cnt; }
  __syncthreads();
  if (t == 0) {
    float f = (bi == bj) ? 1.f : 2.f;
    float S1 = 0.f, S2 = 0.f;
    int C = 0;
    for (int w = 0; w < 4; ++w) { S1 += rs1[w]; S2 += rs2[w]; C += rc[w]; }
    atomicAdd(&accum[0], S1 * f);
    atomicAdd(&accum[1], S2 * f);
    atomicAdd((unsigned*)accum + 2, (unsigned)C * (unsigned)((bi == bj) ? 1 : 2));
  }
}

// ---------------- finalize
__global__ void final_kernel(const float* __restrict__ accum, float* __restrict__ out) {
  unsigned c1 = ((const unsigned*)accum)[2];
  double zn1 = (double)c1;
  double zn2 = (double)NROWS * (double)NROWS - zn1;
  double res = 0.5 * ((double)accum[0] / zn1 + (double)accum[1] / zn2);
  out[0] = (float)res;
}

extern "C" void kernel_launch(void* const* d_in, const int* in_sizes, int n_in,
                              void* d_out, int out_size, void* d_ws, size_t ws_size,
                              hipStream_t stream) {
  const float*     X      = (const float*)d_in[0];
  const long long* lab    = (const long long*)d_in[1];
  const float*     margin = (const float*)d_in[2];
  float*           out    = (float*)d_out;

  char* ws = (char*)d_ws;
  unsigned short* Xb   = (unsigned short*)(ws + OFF_XB);
  float*          sq   = (float*)(ws + OFF_SQ);
  int*            labi = (int*)(ws + OFF_LAB);
  float*          accum= (float*)(ws + OFF_ACC);

  prep_kernel<<<NROWS / 4, 256, 0, stream>>>(X, lab, Xb, sq, labi, accum);
  pair_kernel<<<NPAIR, 256, 0, stream>>>(Xb, sq, labi, margin, accum);
  final_kernel<<<1, 1, 0, stream>>>(accum, out);
}